// Round 6
// baseline (582.956 us; speedup 1.0000x reference)
//
#include <hip/hip_runtime.h>

#define Bb 16
#define Ll 2048
#define Hh 768
#define Dd 64
#define Cc 64
#define NCH 32
#define NTL 12            // 12 h-tiles / G-groups of 64

typedef __attribute__((ext_vector_type(8))) short bf16x8;
typedef __attribute__((ext_vector_type(4))) float f32x4;

__device__ __forceinline__ short f2bf(float f) {
  union { float f; unsigned u; } c;
  c.f = f;
  unsigned r = (c.u + 0x7FFFu + ((c.u >> 16) & 1u)) >> 16;
  return (short)r;
}
__device__ __forceinline__ unsigned pack2(float a, float b) {
  return (unsigned)(unsigned short)f2bf(a) | ((unsigned)(unsigned short)f2bf(b) << 16);
}
__device__ __forceinline__ float bf2f(unsigned short s) {
  union { unsigned u; float f; } c;
  c.u = ((unsigned)s) << 16;
  return c.f;
}

// CK-style barrier: waits LDS ops only; global loads stay in flight.
__device__ __forceinline__ void sync_lds() {
  asm volatile("s_waitcnt lgkmcnt(0)\n\ts_barrier" ::: "memory");
}

// Per-batch inter-block barrier: 32 co-resident blocks (grid fully resident by
// __launch_bounds__(512,4): 2 blocks/CU x 256 CU = 512 = grid). Device-scope
// atomics + threadfence handle XCD L2 non-coherence. Bounded spin as failsafe.
__device__ __forceinline__ void batch_barrier(unsigned* c) {
  __syncthreads();                 // drains all waves' vmem stores (vmcnt 0 before s_barrier)
  if (threadIdx.x == 0) {
    __threadfence();               // release: writeback dirty L2 to L3
    atomicAdd(c, 1u);
    unsigned it = 0;
    while (atomicAdd(c, 0u) < 32u) {
      __builtin_amdgcn_s_sleep(8);
      if (++it > (1u << 21)) break;  // failsafe: fail visibly, never hang
    }
  }
  __syncthreads();
  __threadfence();                 // acquire: invalidate stale L1/L2 before reading peers' data
}

// ---------------- Fused: prep -> (barrier) -> prefix -> (barrier) -> scan ----------------
// block = (b,ch); E and scT persist in LDS across all three phases (no global round-trip).
__global__ __launch_bounds__(512, 4) void fused_kernel(const int* __restrict__ x,
                                                       const float* __restrict__ ae,
                                                       const float* __restrict__ w,
                                                       const float* __restrict__ bx,
                                                       short* __restrict__ Sch,
                                                       unsigned* __restrict__ cnt,
                                                       float* __restrict__ out) {
  const int tid = threadIdx.x;
  const int wv = tid >> 6, lane = tid & 63, quad = lane >> 4, lq = lane & 15;
  const int mt = wv >> 1, np = wv & 1;   // phase A: 8 waves = 4 m-tiles x 2 nt-pairs
  const int bc = blockIdx.x;
  const int b = bc >> 5, ch = bc & 31;
  const int ip = tid & 31, hg = tid >> 5;  // staging: i-pair 0..31, h-group 0..15 (4 h each)

  // 40 KB: sE/sScT persist to phase C; sWT+sF double as the G^T double-buffer.
  __shared__ short lds[20480];
  short* sE   = lds;            // E rows i, cols d (swizzled)        — persists
  short* sWT  = lds + 4096;    // w^T; later G buffer 0
  short* sF   = lds + 8192;    // F rows i cols e; later G buffer 1
  short* sFT  = lds + 12288;   // F^T rows d cols i (swizzled)
  short* sScT = lds + 16384;   // scT rows j, cols i (A-frag linear)  — persists

  // ---- Phase A1: gather E rows -> sE; stage w^T ----
  {
    const int i = tid >> 3, seg = tid & 7;
    const int idx = x[b * Ll + ch * Cc + i];
    const float4* aer = (const float4*)(ae + (size_t)idx * Dd) + seg * 2;
    const float4 a0 = aer[0], a1 = aer[1];
    uint4 p;
    p.x = pack2(a0.x, a0.y); p.y = pack2(a0.z, a0.w);
    p.z = pack2(a1.x, a1.y); p.w = pack2(a1.z, a1.w);
    *(uint4*)&sE[i * 64 + ((seg ^ (i & 7)) << 3)] = p;
    const float4* wr = (const float4*)w;
#pragma unroll
    for (int q = 0; q < 2; ++q) {
      const int fl = q * 512 + tid;
      const int d = fl >> 4, es = (fl & 15) * 4;
      const float4 v = wr[fl];
      const float vv[4] = {v.x, v.y, v.z, v.w};
#pragma unroll
      for (int c = 0; c < 4; ++c) {
        const int e = es + c;
        sWT[e * 64 + (((d >> 3) ^ (e & 7)) << 3) + (d & 7)] = f2bf(vv[c]);
      }
    }
  }
  __syncthreads();

  const int rm = mt * 16 + lq;
  bf16x8 aE[2], aW[2];
#pragma unroll
  for (int ks = 0; ks < 2; ++ks) {
    const int blk = ((ks * 4 + quad) ^ (rm & 7)) << 3;
    aE[ks] = *(const bf16x8*)&sE[rm * 64 + blk];
    aW[ks] = *(const bf16x8*)&sWT[rm * 64 + blk];
  }

  // ---- Phase A2: F[i][e] -> sF ; F^T[d][i] -> sFT ----
#pragma unroll
  for (int t = 0; t < 2; ++t) {
    const int nt = np * 2 + t;
    const int rn = nt * 16 + lq;
    f32x4 accF = {}, accT = {};
#pragma unroll
    for (int ks = 0; ks < 2; ++ks) {
      const int blk = ((ks * 4 + quad) ^ (rn & 7)) << 3;
      const bf16x8 bW = *(const bf16x8*)&sWT[rn * 64 + blk];
      const bf16x8 bE = *(const bf16x8*)&sE[rn * 64 + blk];
      accF = __builtin_amdgcn_mfma_f32_16x16x32_bf16(aE[ks], bW, accF, 0, 0, 0);
      accT = __builtin_amdgcn_mfma_f32_16x16x32_bf16(aW[ks], bE, accT, 0, 0, 0);
    }
#pragma unroll
    for (int r = 0; r < 4; ++r) {
      const int i = mt * 16 + quad * 4 + r;
      const int e = nt * 16 + lq;
      sF[i * 64 + (((e >> 3) ^ (i & 7)) << 3) + (e & 7)] = f2bf(accF[r]);
      const int d2 = mt * 16 + quad * 4 + r;
      const int i2 = nt * 16 + lq;
      sFT[d2 * 64 + (((i2 >> 3) ^ (d2 & 7)) << 3) + (i2 & 7)] = f2bf(accT[r]);
    }
  }
  __syncthreads();   // last reads of sE(A-op)/sWT done; G buffer 0 (sWT) reuse safe after this

  // G^T loader: 64-h group g, shared by phase A state pass and phase C scan.
  float4 rGa, rGb;
  auto load_G = [&](int g) {
    const float* xr = bx + ((size_t)(b * Ll) + ch * Cc + 2 * ip) * Hh + g * 64 + hg * 4;
    rGa = *(const float4*)xr;         // i = 2*ip,   h = g*64+hg*4 ..+4
    rGb = *(const float4*)(xr + Hh);  // i = 2*ip+1
  };
  load_G(0);
  const float s0 = (float)(ch * Cc + 2 * ip + 1), s1 = s0 + 1.0f;
  auto stage_G = [&](short* gbuf) {
    const float A[4] = {rGa.x, rGa.y, rGa.z, rGa.w};
    const float Bv[4] = {rGb.x, rGb.y, rGb.z, rGb.w};
#pragma unroll
    for (int e = 0; e < 4; ++e) {
      const int hl = hg * 4 + e;
      const int sa = hl * 64 + (((ip >> 2) ^ (hl & 7)) << 3) + 2 * (ip & 3);
      *(unsigned*)&gbuf[sa] = pack2(A[e] * s0, Bv[e] * s1);
    }
  };

  // ---- Phase A3: sc[j][i] strict-masked -> sScT (A-frag linear layout, stays in LDS) ----
#pragma unroll
  for (int t = 0; t < 2; ++t) {
    const int nt = np * 2 + t;
    const int rn = nt * 16 + lq;
    f32x4 acc = {};
#pragma unroll
    for (int ks = 0; ks < 2; ++ks) {
      const int blk = ((ks * 4 + quad) ^ (rn & 7)) << 3;
      const bf16x8 bF = *(const bf16x8*)&sF[rn * 64 + blk];
      acc = __builtin_amdgcn_mfma_f32_16x16x32_bf16(aE[ks], bF, acc, 0, 0, 0);
    }
#pragma unroll
    for (int r = 0; r < 4; ++r) {
      const int j = mt * 16 + quad * 4 + r;
      const int i = nt * 16 + lq;
      sScT[j * 64 + i] = f2bf(i < j ? acc[r] : 0.f);
    }
  }

  // F^T B-fragments: each wave only its 2 d-tiles
  bf16x8 bFT[2][2];
#pragma unroll
  for (int tl = 0; tl < 2; ++tl) {
    const int rn = ((wv >> 2) * 2 + tl) * 16 + lq;
#pragma unroll
    for (int ks = 0; ks < 2; ++ks) {
      const int blk = ((ks * 4 + quad) ^ (rn & 7)) << 3;
      bFT[tl][ks] = *(const bf16x8*)&sFT[rn * 64 + blk];
    }
  }

  // ---- Phase A4: 12 groups x 64 h: Schunk[h,d] = mfma(G^T rows h, F^T rows d) -> global ----
  short* So = Sch + (size_t)bc * (Hh * Dd);
#pragma unroll 2
  for (int g = 0; g < NTL; ++g) {
    short* gbuf = lds + 4096 + (g & 1) * 4096;
    stage_G(gbuf);
    if (g + 1 < NTL) load_G(g + 1);
    sync_lds();
    const int rh = (wv & 3) * 16 + lq;
    bf16x8 aG[2];
#pragma unroll
    for (int ks = 0; ks < 2; ++ks)
      aG[ks] = *(const bf16x8*)&gbuf[rh * 64 + (((ks * 4 + quad) ^ (rh & 7)) << 3)];
#pragma unroll
    for (int tl = 0; tl < 2; ++tl) {
      f32x4 acc = {};
#pragma unroll
      for (int ks = 0; ks < 2; ++ks)
        acc = __builtin_amdgcn_mfma_f32_16x16x32_bf16(aG[ks], bFT[tl][ks], acc, 0, 0, 0);
      const int nt = (wv >> 2) * 2 + tl;
#pragma unroll
      for (int r = 0; r < 4; ++r) {
        const int h = g * 64 + (wv & 3) * 16 + quad * 4 + r;
        So[h * 64 + nt * 16 + lq] = f2bf(acc[r]);
      }
    }
  }

  batch_barrier(&cnt[b]);   // all 32 chunks of batch b published their Schunk

  // ---- Phase B: in-place EXCLUSIVE prefix over the 32 planes of batch b ----
  // 32 blocks x 512 threads = 16384 threads for 12288 uint2-columns.
  {
    const int col = ch * 512 + tid;
    if (col < (Hh * Dd / 4)) {
      uint2* base = (uint2*)Sch + (size_t)b * NCH * (Hh * Dd / 4) + col;
      const int stride = Hh * Dd / 4;
      float4 acc = {0.f, 0.f, 0.f, 0.f};
#pragma unroll
      for (int hf = 0; hf < 2; ++hf) {
        uint2 va[16];
#pragma unroll
        for (int s = 0; s < 16; ++s) va[s] = base[(hf * 16 + s) * stride];
#pragma unroll
        for (int s = 0; s < 16; ++s) {
          uint2 o;
          o.x = pack2(acc.x, acc.y);
          o.y = pack2(acc.z, acc.w);
          base[(hf * 16 + s) * stride] = o;
          acc.x += bf2f((unsigned short)(va[s].x & 0xffffu));
          acc.y += bf2f((unsigned short)(va[s].x >> 16));
          acc.z += bf2f((unsigned short)(va[s].y & 0xffffu));
          acc.w += bf2f((unsigned short)(va[s].y >> 16));
        }
      }
    }
  }

  batch_barrier(&cnt[16 + b]);  // prefix planes of batch b complete

  // ---- Phase C: scan — 12 h-tiles; scT/E frags come straight from LDS ----
  const int jt = wv & 3, hth = wv >> 2;
  const int rj = jt * 16 + lq;
  bf16x8 aC1[2], aC2[2];
#pragma unroll
  for (int ks = 0; ks < 2; ++ks) {
    aC1[ks] = *(const bf16x8*)&sScT[rj * 64 + (ks * 4 + quad) * 8];
    aC2[ks] = *(const bf16x8*)&sE[rj * 64 + (((ks * 4 + quad) ^ (rj & 7)) << 3)];
  }
  const short* Sp = Sch + (size_t)bc * (Hh * Dd);
  float inv[4];
  size_t rowb[4];
#pragma unroll
  for (int r = 0; r < 4; ++r) {
    const int gj = ch * Cc + jt * 16 + quad * 4 + r;
    inv[r] = 1.0f / (float)(gj + 1);
    rowb[r] = ((size_t)(b * Ll) + gj) * Hh;
  }
  bf16x8 stC[2][2], stN[2][2];
  auto load_S = [&](int t, bf16x8 st[2][2]) {
#pragma unroll
    for (int k = 0; k < 2; ++k) {
      const int h = t * 64 + (hth * 2 + k) * 16 + lq;
#pragma unroll
      for (int ks = 0; ks < 2; ++ks)
        st[k][ks] = *(const bf16x8*)(Sp + h * 64 + (ks * 4 + quad) * 8);
    }
  };
  load_G(0);
  load_S(0, stC);
#pragma unroll
  for (int t = 0; t < NTL; ++t) {
    short* gbuf = lds + 4096 + (t & 1) * 4096;
    stage_G(gbuf);
    if (t + 1 < NTL) load_G(t + 1);
    sync_lds();
#pragma unroll
    for (int k = 0; k < 2; ++k) {
      const int rh = (hth * 2 + k) * 16 + lq;
      f32x4 accO = {};
#pragma unroll
      for (int ks = 0; ks < 2; ++ks) {
        const bf16x8 gv = *(const bf16x8*)&gbuf[rh * 64 + (((ks * 4 + quad) ^ (rh & 7)) << 3)];
        accO = __builtin_amdgcn_mfma_f32_16x16x32_bf16(aC1[ks], gv, accO, 0, 0, 0);
        accO = __builtin_amdgcn_mfma_f32_16x16x32_bf16(aC2[ks], stC[k][ks], accO, 0, 0, 0);
      }
      const int hcol = t * 64 + (hth * 2 + k) * 16 + lq;
#pragma unroll
      for (int r = 0; r < 4; ++r) {
        const size_t off = rowb[r] + hcol;
        out[off] = bx[off] + accO[r] * inv[r];
      }
    }
    if (t + 1 < NTL) {
      load_S(t + 1, stN);
#pragma unroll
      for (int k = 0; k < 2; ++k)
#pragma unroll
        for (int ks = 0; ks < 2; ++ks) stC[k][ks] = stN[k][ks];
    }
  }
}

extern "C" void kernel_launch(void* const* d_in, const int* in_sizes, int n_in,
                              void* d_out, int out_size, void* d_ws, size_t ws_size,
                              hipStream_t stream) {
  (void)in_sizes; (void)n_in; (void)out_size; (void)ws_size;
  const float* bx = (const float*)d_in[0];
  const int* x = (const int*)d_in[1];
  const float* ae = (const float*)d_in[2];
  const float* w = (const float*)d_in[3];
  float* out = (float*)d_out;
  short* Sch = (short*)d_ws;                              // 512*768*64 bf16 = 50.3 MB
  unsigned* cnt = (unsigned*)(Sch + (size_t)512 * Hh * Dd);  // 32 barrier counters

  hipMemsetAsync(cnt, 0, 128, stream);  // graph-captured; re-zeroed every replay
  fused_kernel<<<Bb * NCH, 512, 0, stream>>>(x, ae, w, bx, Sch, cnt, out);
}

// Round 8
// 261.425 us; speedup vs baseline: 2.2299x; 2.2299x over previous
//
#include <hip/hip_runtime.h>

#define Bb 16
#define Ll 2048
#define Hh 768
#define Dd 64
#define Cc 64
#define HC 64             // h-tile width for scan (256 B rows -> full-line stores)
#define NT (Hh / HC)      // 12 h-tiles
#define NCH (Ll / Cc)     // 32 chunks
#define NGH 3             // prep phase-2: 3 groups x 128 h per h-block (2 h-blocks)
#define TG 4              // scan: tiles per block
#define NTG (NT / TG)     // 3 tile-groups

typedef __attribute__((ext_vector_type(8))) short bf16x8;
typedef __attribute__((ext_vector_type(4))) float f32x4;

__device__ __forceinline__ short f2bf(float f) {
  union { float f; unsigned u; } c;
  c.f = f;
  unsigned r = (c.u + 0x7FFFu + ((c.u >> 16) & 1u)) >> 16;
  return (short)r;
}
__device__ __forceinline__ unsigned pack2(float a, float b) {
  return (unsigned)(unsigned short)f2bf(a) | ((unsigned)(unsigned short)f2bf(b) << 16);
}
__device__ __forceinline__ float bf2f(unsigned short s) {
  union { unsigned u; float f; } c;
  c.u = ((unsigned)s) << 16;
  return c.f;
}

// CK-style barrier: waits LDS ops only; global prefetch loads stay in flight.
__device__ __forceinline__ void sync_lds() {
  asm volatile("s_waitcnt lgkmcnt(0)\n\ts_barrier" ::: "memory");
}

// ---------------- Prep (512 thr, h-split 2-way): per (hb, b,chunk) ----------------
// hb=0 also writes E, scT (frag layout). Each half writes its 384-h slab of
// Schunk[h,d] = sum_{i in chunk} (global_i+1)*bx[i,h]*F[i,d]
__global__ __launch_bounds__(512) void prep_kernel(const int* __restrict__ x,
                                                   const float* __restrict__ ae,
                                                   const float* __restrict__ w,
                                                   const float* __restrict__ bx,
                                                   short* __restrict__ Eg,
                                                   short* __restrict__ scTg,
                                                   short* __restrict__ Sch) {
  const int tid = threadIdx.x;
  const int wv = tid >> 6, lane = tid & 63, quad = lane >> 4, lq = lane & 15;
  const int mt = wv >> 1, np = wv & 1;   // 8 waves: m-tile 0..3, nt-pair 0..1
  const int hb = blockIdx.x >> 9;        // h-block 0..1 (same bc%8 -> same XCD as sibling)
  const int bc = blockIdx.x & 511;
  const int b = bc >> 5, ch = bc & 31;
  const size_t gb = (size_t)bc * 4096;
  // 32 KB aliased pool: phase1 = sE|sWT|sF|sFT; phase2 = two 16 KB G^T buffers
  __shared__ short pool[4 * 4096];
  short* sE  = pool;
  short* sWT = pool + 4096;
  short* sF  = pool + 8192;
  short* sFT = pool + 12288;

  // ---- Phase 1a: gather E rows -> sE (+ Eg from hb=0); stage w^T ----
  {
    const int i = tid >> 3, seg = tid & 7;
    const int idx = x[b * Ll + ch * Cc + i];
    const float4* aer = (const float4*)(ae + (size_t)idx * Dd) + seg * 2;
    const float4 a0 = aer[0], a1 = aer[1];
    uint4 p;
    p.x = pack2(a0.x, a0.y); p.y = pack2(a0.z, a0.w);
    p.z = pack2(a1.x, a1.y); p.w = pack2(a1.z, a1.w);
    *(uint4*)&sE[i * 64 + ((seg ^ (i & 7)) << 3)] = p;
    if (hb == 0) *(uint4*)(Eg + gb + i * 64 + seg * 8) = p;
    const float4* wr = (const float4*)w;
#pragma unroll
    for (int q = 0; q < 2; ++q) {
      const int fl = q * 512 + tid;
      const int d = fl >> 4, es = (fl & 15) * 4;
      const float4 v = wr[fl];
      const float vv[4] = {v.x, v.y, v.z, v.w};
#pragma unroll
      for (int c = 0; c < 4; ++c) {
        const int e = es + c;
        sWT[e * 64 + (((d >> 3) ^ (e & 7)) << 3) + (d & 7)] = f2bf(vv[c]);
      }
    }
  }
  __syncthreads();

  const int rm = mt * 16 + lq;
  bf16x8 aE[2], aW[2];
#pragma unroll
  for (int ks = 0; ks < 2; ++ks) {
    const int blk = ((ks * 4 + quad) ^ (rm & 7)) << 3;
    aE[ks] = *(const bf16x8*)&sE[rm * 64 + blk];
    aW[ks] = *(const bf16x8*)&sWT[rm * 64 + blk];
  }

  // ---- Phase 1b: F[i][e] -> sF ; F^T[d][i] -> sFT ----
#pragma unroll
  for (int t = 0; t < 2; ++t) {
    const int nt = np * 2 + t;
    const int rn = nt * 16 + lq;
    f32x4 accF = {}, accT = {};
#pragma unroll
    for (int ks = 0; ks < 2; ++ks) {
      const int blk = ((ks * 4 + quad) ^ (rn & 7)) << 3;
      const bf16x8 bW = *(const bf16x8*)&sWT[rn * 64 + blk];
      const bf16x8 bE = *(const bf16x8*)&sE[rn * 64 + blk];
      accF = __builtin_amdgcn_mfma_f32_16x16x32_bf16(aE[ks], bW, accF, 0, 0, 0);
      accT = __builtin_amdgcn_mfma_f32_16x16x32_bf16(aW[ks], bE, accT, 0, 0, 0);
    }
#pragma unroll
    for (int r = 0; r < 4; ++r) {
      const int i = mt * 16 + quad * 4 + r;
      const int e = nt * 16 + lq;
      sF[i * 64 + (((e >> 3) ^ (i & 7)) << 3) + (e & 7)] = f2bf(accF[r]);
      const int d2 = mt * 16 + quad * 4 + r;
      const int i2 = nt * 16 + lq;
      sFT[d2 * 64 + (((i2 >> 3) ^ (d2 & 7)) << 3) + (i2 & 7)] = f2bf(accT[r]);
    }
  }
  __syncthreads();   // last reads of sE/sWT above; G-buffer A reuse safe after this

  // prefetch this h-block's first G group while scT computes
  const int ip = tid & 31, hg = tid >> 5;   // ip: i-pair 0..31; hg: 0..15 -> 8 h each (128 h/group)
  float4 rGa[2], rGb[2];
  auto load_G = [&](int g) {   // g in [0, 6): 128-h group within the full 768
    const float* xr = bx + ((size_t)(b * Ll) + ch * Cc + 2 * ip) * Hh + g * 128 + hg * 8;
    rGa[0] = *(const float4*)(xr);
    rGa[1] = *(const float4*)(xr + 4);
    rGb[0] = *(const float4*)(xr + Hh);
    rGb[1] = *(const float4*)(xr + Hh + 4);
  };
  const int g0 = hb * NGH;   // hb=0: groups 0..2 (h 0..383); hb=1: groups 3..5 (h 384..767)
  load_G(g0);

  // ---- Phase 1c: sc[j][i] strict-masked -> scTg (frag layout), hb=0 only ----
#pragma unroll
  for (int t = 0; t < 2; ++t) {
    const int nt = np * 2 + t;
    const int rn = nt * 16 + lq;
    f32x4 acc = {};
#pragma unroll
    for (int ks = 0; ks < 2; ++ks) {
      const int blk = ((ks * 4 + quad) ^ (rn & 7)) << 3;
      const bf16x8 bF = *(const bf16x8*)&sF[rn * 64 + blk];
      acc = __builtin_amdgcn_mfma_f32_16x16x32_bf16(aE[ks], bF, acc, 0, 0, 0);
    }
    if (hb == 0) {
#pragma unroll
      for (int r = 0; r < 4; ++r) {
        const int j = mt * 16 + quad * 4 + r;
        const int i = nt * 16 + lq;
        scTg[gb + j * 64 + i] = f2bf(i < j ? acc[r] : 0.f);
      }
    }
  }

  // F^T B-fragments (rows d, k = i) — every wave needs all 4 d-tiles
  bf16x8 bFT[4][2];
#pragma unroll
  for (int nt = 0; nt < 4; ++nt) {
    const int rn = nt * 16 + lq;
#pragma unroll
    for (int ks = 0; ks < 2; ++ks) {
      const int blk = ((ks * 4 + quad) ^ (rn & 7)) << 3;
      bFT[nt][ks] = *(const bf16x8*)&sFT[rn * 64 + blk];
    }
  }

  // ---- Phase 2: 3 groups x 128 h (this h-block's 384-h slab) ----
  short* So = Sch + (size_t)bc * (Hh * Dd);
#pragma unroll
  for (int gi = 0; gi < NGH; ++gi) {
    const int g = g0 + gi;          // within [g0, g0+3): h = g*128 .. g*128+127 <= 767
    short* gbuf = pool + (gi & 1) * 8192;
    {
      const float s0 = (float)(ch * Cc + 2 * ip + 1), s1 = (float)(ch * Cc + 2 * ip + 2);
      const float A[8] = {rGa[0].x, rGa[0].y, rGa[0].z, rGa[0].w,
                          rGa[1].x, rGa[1].y, rGa[1].z, rGa[1].w};
      const float Bv[8] = {rGb[0].x, rGb[0].y, rGb[0].z, rGb[0].w,
                           rGb[1].x, rGb[1].y, rGb[1].z, rGb[1].w};
#pragma unroll
      for (int e = 0; e < 8; ++e) {
        const int hl = hg * 8 + e;   // 0..127
        const int sa = hl * 64 + (((ip >> 2) ^ (hl & 7)) << 3) + 2 * (ip & 3);
        *(unsigned*)&gbuf[sa] = pack2(A[e] * s0, Bv[e] * s1);
      }
    }
    if (gi + 1 < NGH) load_G(g + 1);
    sync_lds();
    const int rh = wv * 16 + lq;   // this wave's 16 h-rows within the 128-row buffer
    bf16x8 aG[2];
#pragma unroll
    for (int ks = 0; ks < 2; ++ks) {
      const int blk = ((ks * 4 + quad) ^ (rh & 7)) << 3;
      aG[ks] = *(const bf16x8*)&gbuf[rh * 64 + blk];
    }
#pragma unroll
    for (int nt = 0; nt < 4; ++nt) {
      f32x4 acc = {};
#pragma unroll
      for (int ks = 0; ks < 2; ++ks)
        acc = __builtin_amdgcn_mfma_f32_16x16x32_bf16(aG[ks], bFT[nt][ks], acc, 0, 0, 0);
#pragma unroll
      for (int r = 0; r < 4; ++r) {
        const int h = g * 128 + wv * 16 + quad * 4 + r;   // < 768
        So[h * 64 + nt * 16 + lq] = f2bf(acc[r]);
      }
    }
  }
}

// ---------------- Prefix: in-place EXCLUSIVE prefix over 32 chunk planes per b ----------------
__global__ __launch_bounds__(256) void prefix_kernel(short* __restrict__ Sch) {
  const int b = blockIdx.x / 48;                        // 48 blocks per b
  const int v = (blockIdx.x % 48) * 256 + threadIdx.x;  // uint2 index in plane [0,12288)
  uint2* base = (uint2*)(Sch + (size_t)b * NCH * (Hh * Dd)) + v;
  const int stride = Hh * Dd / 4;  // uint2 per plane
  uint2 va[NCH];
#pragma unroll
  for (int s = 0; s < NCH; ++s) va[s] = base[s * stride];  // load all first (no RW hazard)
  float4 acc = {0.f, 0.f, 0.f, 0.f};
#pragma unroll
  for (int s = 0; s < NCH; ++s) {
    uint2 o;
    o.x = pack2(acc.x, acc.y);
    o.y = pack2(acc.z, acc.w);
    base[s * stride] = o;  // exclusive prefix (plane 0 = zeros)
    acc.x += bf2f((unsigned short)(va[s].x & 0xffffu));
    acc.y += bf2f((unsigned short)(va[s].x >> 16));
    acc.z += bf2f((unsigned short)(va[s].y & 0xffffu));
    acc.w += bf2f((unsigned short)(va[s].y >> 16));
  }
}

// ---------------- Scan: per (tile-group, b, ch) — 4 pipelined h-tiles sharing frags ----------------
// out[j,h] = bx[j,h] + (1/(j+1)) * [ sum_{i<j in ch} sc[j,i]*G[i,h]  +  sum_d E[j,d]*Sprefix[h,d] ]
__global__ __launch_bounds__(256) void scan_kernel(const float* __restrict__ bx,
                                                   const short* __restrict__ Eg,
                                                   const short* __restrict__ scTg,
                                                   const short* __restrict__ STg,
                                                   float* __restrict__ out) {
  const int s = blockIdx.x;             // [0, 3*512): bc%8 fixes XCD for all 3 tile-groups of a bc
  const int tg = s >> 9;                // tile-group 0..2
  const int bc = s & 511;               // (b,ch)
  const int b = bc >> 5, ch = bc & 31;
  const int tid = threadIdx.x;
  const int w = tid >> 6, lane = tid & 63, quad = lane >> 4, lq = lane & 15;
  const int ip = tid & 31, hg = tid >> 5;
  const int rj = w * 16 + lq;

  __shared__ short sGT[2][64 * 64];  // G^T rows h(local), cols i (swizzled), double-buffered

  // loop-invariant fragments: scT rows j (k=i), E rows j (k=d) — loaded ONCE per block
  bf16x8 aC1[2], aC2[2];
  {
    const size_t tb = (size_t)bc * 4096;
#pragma unroll
    for (int ks = 0; ks < 2; ++ks) {
      const int o = rj * 64 + (ks * 4 + quad) * 8;
      aC1[ks] = *(const bf16x8*)(scTg + tb + o);
      aC2[ks] = *(const bf16x8*)(Eg + tb + o);
    }
  }
  const short* Sp = STg + (size_t)bc * (Hh * Dd);

  float4 rGa[2], rGb[2];
  bf16x8 stF[4][2];
  auto load_G = [&](int tl) {
    const float* xr = bx + ((size_t)(b * Ll) + ch * Cc + 2 * ip) * Hh + tl * HC + hg * 8;
    rGa[0] = *(const float4*)(xr);
    rGa[1] = *(const float4*)(xr + 4);
    rGb[0] = *(const float4*)(xr + Hh);
    rGb[1] = *(const float4*)(xr + Hh + 4);
  };
  auto load_S = [&](int tl) {
#pragma unroll
    for (int ht = 0; ht < 4; ++ht) {
      const int h = tl * HC + ht * 16 + lq;
#pragma unroll
      for (int ks = 0; ks < 2; ++ks)
        stF[ht][ks] = *(const bf16x8*)(Sp + h * 64 + (ks * 4 + quad) * 8);
    }
  };

  load_G(tg * TG);
  load_S(tg * TG);

  const float s0 = (float)(ch * Cc + 2 * ip + 1), s1 = (float)(ch * Cc + 2 * ip + 2);

#pragma unroll
  for (int t = 0; t < TG; ++t) {
    const int tl = tg * TG + t;
    short* gbuf = sGT[t & 1];
    // stage G^T (scaled bx, h x i) from regs into LDS
    {
      const float A[8] = {rGa[0].x, rGa[0].y, rGa[0].z, rGa[0].w,
                          rGa[1].x, rGa[1].y, rGa[1].z, rGa[1].w};
      const float Bv[8] = {rGb[0].x, rGb[0].y, rGb[0].z, rGb[0].w,
                           rGb[1].x, rGb[1].y, rGb[1].z, rGb[1].w};
#pragma unroll
      for (int e = 0; e < 8; ++e) {
        const int hl = hg * 8 + e;
        const int sa = hl * 64 + (((ip >> 2) ^ (hl & 7)) << 3) + 2 * (ip & 3);
        *(unsigned*)&gbuf[sa] = pack2(A[e] * s0, Bv[e] * s1);
      }
    }
    if (t + 1 < TG) load_G(tl + 1);   // next tile's G in flight across the barrier
    sync_lds();                        // lgkm-only: global loads keep flying

#pragma unroll
    for (int ht = 0; ht < 4; ++ht) {
      const int rh = ht * 16 + lq;
      f32x4 accO = {};
#pragma unroll
      for (int ks = 0; ks < 2; ++ks) {
        const int blk = ((ks * 4 + quad) ^ (rh & 7)) << 3;
        const bf16x8 gv = *(const bf16x8*)&gbuf[rh * 64 + blk];
        accO = __builtin_amdgcn_mfma_f32_16x16x32_bf16(aC1[ks], gv, accO, 0, 0, 0);
        accO = __builtin_amdgcn_mfma_f32_16x16x32_bf16(aC2[ks], stF[ht][ks], accO, 0, 0, 0);
      }
#pragma unroll
      for (int r = 0; r < 4; ++r) {
        const int gj = ch * Cc + w * 16 + quad * 4 + r;
        const size_t off = ((size_t)(b * Ll) + gj) * Hh + tl * HC + ht * 16 + lq;
        out[off] = bx[off] + accO[r] * (1.0f / (float)(gj + 1));
      }
    }
    if (t + 1 < TG) load_S(tl + 1);   // stF regs free after MFMAs above
  }
}

extern "C" void kernel_launch(void* const* d_in, const int* in_sizes, int n_in,
                              void* d_out, int out_size, void* d_ws, size_t ws_size,
                              hipStream_t stream) {
  (void)in_sizes; (void)n_in; (void)out_size; (void)ws_size;
  const float* bx = (const float*)d_in[0];
  const int* x = (const int*)d_in[1];
  const float* ae = (const float*)d_in[2];
  const float* w = (const float*)d_in[3];
  float* out = (float*)d_out;
  short* Eg = (short*)d_ws;                        // 512*4096 bf16 = 4 MB
  short* scTg = Eg + (size_t)512 * 4096;           // 4 MB
  short* Sch = scTg + (size_t)512 * 4096;          // 512*768*64 bf16 = 50.3 MB (in-place -> STg)

  prep_kernel<<<2 * Bb * NCH, 512, 0, stream>>>(x, ae, w, bx, Eg, scTg, Sch);
  prefix_kernel<<<Bb * 48, 256, 0, stream>>>(Sch);
  scan_kernel<<<NTG * Bb * NCH, 256, 0, stream>>>(bx, Eg, scTg, Sch, out);
}